// Round 1
// baseline (104.136 us; speedup 1.0000x reference)
//
#include <hip/hip_runtime.h>
#include <hip/hip_bf16.h>

#define BN 512   // batch
#define DD 512   // feature dim
#define LL 24    // label dim
#define DSTR 516 // padded LDS row stride (floats): 516 mod 32 = 4 -> breaks row aliasing

typedef __attribute__((ext_vector_type(8))) short short8;  // 8 bf16 = 4 VGPR
typedef __attribute__((ext_vector_type(4))) float f32x4;

// ws layout (float words): [0, 64) per-block slots: block b -> {sum(f32), cnt(u32)}

__device__ __forceinline__ float dist_val(float d2, bool diag) {
    d2 = fmaxf(d2, 0.0f);
    float d = sqrtf(d2);
    return diag ? 0.0f : d;
}

__device__ __forceinline__ unsigned pk_bf16(float lo, float hi) {
    __hip_bfloat162 p = __float22bfloat162_rn(make_float2(lo, hi));
    unsigned u;
    __builtin_memcpy(&u, &p, 4);     // type-pun; bit_cast rejects non-trivial ctor
    return u;
}

// pack 8 f32 -> bf16 fragment via v_cvt_pk_bf16_f32, accumulate sum of squares
__device__ __forceinline__ short8 pack8_pk(float4 x, float4 y, float& nrm) {
    nrm = fmaf(x.x, x.x, nrm); nrm = fmaf(x.y, x.y, nrm);
    nrm = fmaf(x.z, x.z, nrm); nrm = fmaf(x.w, x.w, nrm);
    nrm = fmaf(y.x, y.x, nrm); nrm = fmaf(y.y, y.y, nrm);
    nrm = fmaf(y.z, y.z, nrm); nrm = fmaf(y.w, y.w, nrm);
    union { uint4 u; short8 s; } cv;
    cv.u.x = pk_bf16(x.x, x.y);
    cv.u.y = pk_bf16(x.z, x.w);
    cv.u.z = pk_bf16(y.x, y.y);
    cv.u.w = pk_bf16(y.z, y.w);
    return cv.s;
}

// ---------------- fused kernel: dist panel in LDS + in-block triplet ---------
// One block per 16-row i-panel (32 blocks). 1024 threads = 16 waves.
// Phase 1: wave w computes j-tiles {w, w+16} of the 16x512 distance panel
//          (A fragments shared across both tiles), writes to LDS.
// Phase 2: wave w reduces triplet loss for global row ib+w from the LDS panel.
// Each block writes its partial (sum, cnt) to its own slot -- no atomics,
// no zero-init (workspace is poisoned; every block overwrites its slot).
__global__ __launch_bounds__(1024) void fused_kernel(
    const float* __restrict__ S, const int* __restrict__ labels,
    float* __restrict__ slots)
{
    __shared__ unsigned mlds[BN];          // label masks, all 512 rows
    __shared__ float    Dp[16 * DSTR];     // 16 x 512 distance panel (padded)
    __shared__ float    wsum[16];
    __shared__ unsigned wcnt[16];

    const int t    = threadIdx.x;
    const int lane = t & 63;
    const int w    = t >> 6;               // wave id 0..15
    const int ib   = blockIdx.x * 16;      // i-panel base row

    // ---- label masks for ALL rows (threads 0..511, one row each) ----
    if (t < BN) {
        const int4* lab4 = (const int4*)(labels + (size_t)t * LL);
        unsigned m = 0;
#pragma unroll
        for (int v = 0; v < 6; v++) {      // 24 ints = 6 x int4 (96B row, 16B aligned)
            int4 x = lab4[v];
            m |= (x.x ? 1u : 0u) << (4 * v)
               | (x.y ? 1u : 0u) << (4 * v + 1)
               | (x.z ? 1u : 0u) << (4 * v + 2)
               | (x.w ? 1u : 0u) << (4 * v + 3);
        }
        mlds[t] = m;
    }

    // ---- phase 1: MFMA distance tiles (verified layout: col=lane&15, row=half*4+p)
    const int r    = lane & 15;
    const int half = lane >> 4;
    const int kb   = half * 8;
    const int j0   = w * 16;               // j-tile 0 base col
    const int j1   = (w + 16) * 16;        // j-tile 1 base col

    const float* pA  = S + (size_t)(ib + r) * DD + kb;
    const float* pB0 = S + (size_t)(j0 + r) * DD + kb;
    const float* pB1 = S + (size_t)(j1 + r) * DD + kb;

    f32x4 acc0 = {0.f, 0.f, 0.f, 0.f}, acc1 = {0.f, 0.f, 0.f, 0.f};
    float nA = 0.f, nB0 = 0.f, nB1 = 0.f;

    float4 ax  = *(const float4*)pA,        ay  = *(const float4*)(pA + 4);
    float4 b0x = *(const float4*)pB0,       b0y = *(const float4*)(pB0 + 4);
    float4 b1x = *(const float4*)pB1,       b1y = *(const float4*)(pB1 + 4);

    for (int k0 = 0; k0 < DD; k0 += 32) {
        const int kn = k0 + 32;
        float4 nax = ax, nay = ay, nb0x = b0x, nb0y = b0y, nb1x = b1x, nb1y = b1y;
        if (kn < DD) {                     // uniform: prefetch next k-step
            nax  = *(const float4*)(pA + kn);  nay  = *(const float4*)(pA + kn + 4);
            nb0x = *(const float4*)(pB0 + kn); nb0y = *(const float4*)(pB0 + kn + 4);
            nb1x = *(const float4*)(pB1 + kn); nb1y = *(const float4*)(pB1 + kn + 4);
        }
        short8 af  = pack8_pk(ax,  ay,  nA);   // A packed once, used for both tiles
        short8 bf0 = pack8_pk(b0x, b0y, nB0);
        short8 bf1 = pack8_pk(b1x, b1y, nB1);
        acc0 = __builtin_amdgcn_mfma_f32_16x16x32_bf16(af, bf0, acc0, 0, 0, 0);
        acc1 = __builtin_amdgcn_mfma_f32_16x16x32_bf16(af, bf1, acc1, 0, 0, 0);
        ax = nax; ay = nay; b0x = nb0x; b0y = nb0y; b1x = nb1x; b1y = nb1y;
    }

    // norms: row covered by lanes {r, r+16, r+32, r+48} (disjoint k) -> reduce
    nA  += __shfl_xor(nA, 16);  nA  += __shfl_xor(nA, 32);
    nB0 += __shfl_xor(nB0, 16); nB0 += __shfl_xor(nB0, 32);
    nB1 += __shfl_xor(nB1, 16); nB1 += __shfl_xor(nB1, 32);

#pragma unroll
    for (int p = 0; p < 4; p++) {
        const int il = half * 4 + p;       // local i row
        const int gi = ib + il;
        const float ni = __shfl(nA, il);   // lane il holds norm of row ib+il
        Dp[il * DSTR + j0 + r] = dist_val(ni + nB0 - 2.f * acc0[p], gi == (j0 + r));
        Dp[il * DSTR + j1 + r] = dist_val(ni + nB1 - 2.f * acc1[p], gi == (j1 + r));
    }

    __syncthreads();

    // ---- phase 2: wave w reduces row ib+w from the LDS panel ----
    const unsigned mi = mlds[ib + w];
    float dv[8]; unsigned long long pb[8];
#pragma unroll
    for (int c = 0; c < 8; c++) {
        const int j = c * 64 + lane;
        dv[c] = Dp[w * DSTR + j];
        pb[c] = __ballot((mi & mlds[j]) != 0u);   // positive ballot (wave-uniform)
    }
    float sum = 0.f; unsigned cnt = 0;
#pragma unroll
    for (int c = 0; c < 8; c++) {
        unsigned long long nb = ~pb[c];           // negatives (rare: ~0.5/row)
        while (nb) {                              // wave-uniform loop
            const int k = __ffsll(nb) - 1;
            nb &= nb - 1;
            const float dk = __shfl(dv[c], k);
#pragma unroll
            for (int c2 = 0; c2 < 8; c2++) {
                if ((pb[c2] >> lane) & 1ull) {    // this lane's j is positive
                    const float v = dv[c2] - dk;
                    sum += fmaxf(v, 0.0f);
                    cnt += (v > 1e-16f) ? 1u : 0u;
                }
            }
        }
    }
#pragma unroll
    for (int off = 32; off > 0; off >>= 1) {
        sum += __shfl_down(sum, off);
        cnt += __shfl_down(cnt, off);
    }
    if (lane == 0) { wsum[w] = sum; wcnt[w] = cnt; }
    __syncthreads();

    if (t == 0) {
        float s = 0.f; unsigned c = 0;
#pragma unroll
        for (int q = 0; q < 16; q++) { s += wsum[q]; c += wcnt[q]; }
        slots[blockIdx.x * 2]                   = s;   // plain stores: kernel
        ((unsigned*)slots)[blockIdx.x * 2 + 1]  = c;   // boundary = release
    }
}

// ---------------- finalize: sum 32 slots, divide ----------------------------
__global__ void finalize_kernel(const float* __restrict__ slots, float* __restrict__ out) {
    const int t = threadIdx.x;                 // 64
    float s = 0.f; unsigned c = 0;
    if (t < 32) {
        s = slots[t * 2];
        c = ((const unsigned*)slots)[t * 2 + 1];
    }
#pragma unroll
    for (int off = 32; off > 0; off >>= 1) {
        s += __shfl_down(s, off);
        c += __shfl_down(c, off);
    }
    if (t == 0) out[0] = s / ((float)c + 1e-16f);
}

extern "C" void kernel_launch(void* const* d_in, const int* in_sizes, int n_in,
                              void* d_out, int out_size, void* d_ws, size_t ws_size,
                              hipStream_t stream) {
    const float* src    = (const float*)d_in[0];
    const int*   labels = (const int*)d_in[1];
    float* slots = (float*)d_ws;

    hipLaunchKernelGGL(fused_kernel,    dim3(32), dim3(1024), 0, stream, src, labels, slots);
    hipLaunchKernelGGL(finalize_kernel, dim3(1),  dim3(64),   0, stream, slots, (float*)d_out);
}

// Round 2
// 71.434 us; speedup vs baseline: 1.4578x; 1.4578x over previous
//
#include <hip/hip_runtime.h>
#include <hip/hip_bf16.h>

#define BN 512   // batch
#define DD 512   // feature dim
#define LL 24    // label dim

typedef __attribute__((ext_vector_type(8))) short short8;  // 8 bf16 = 4 VGPR
typedef __attribute__((ext_vector_type(4))) float f32x4;

// ws layout (float words):
//   [0,512)              masks (u32)
//   [512, 512+262144)    Dm (f32, 512x512)
//   [262656 + {0,1,2}]   accum: sum(f32), cnt(u32), done(u32)

__device__ __forceinline__ float dist_val(float d2, bool diag) {
    d2 = fmaxf(d2, 0.0f);
    float d = sqrtf(d2);
    return diag ? 0.0f : d;
}

__device__ __forceinline__ unsigned pk_bf16(float lo, float hi) {
    __hip_bfloat162 p = __float22bfloat162_rn(make_float2(lo, hi));
    unsigned u;
    __builtin_memcpy(&u, &p, 4);     // type-pun; bit_cast rejects non-trivial ctor
    return u;
}

// pack 8 f32 -> bf16 fragment via v_cvt_pk_bf16_f32, accumulate sum of squares
__device__ __forceinline__ short8 pack8_pk(float4 x, float4 y, float& nrm) {
    nrm = fmaf(x.x, x.x, nrm); nrm = fmaf(x.y, x.y, nrm);
    nrm = fmaf(x.z, x.z, nrm); nrm = fmaf(x.w, x.w, nrm);
    nrm = fmaf(y.x, y.x, nrm); nrm = fmaf(y.y, y.y, nrm);
    nrm = fmaf(y.z, y.z, nrm); nrm = fmaf(y.w, y.w, nrm);
    union { uint4 u; short8 s; } cv;
    cv.u.x = pk_bf16(x.x, x.y);
    cv.u.y = pk_bf16(x.z, x.w);
    cv.u.z = pk_bf16(y.x, y.y);
    cv.u.w = pk_bf16(y.z, y.w);
    return cv.s;
}

// ---------- kernel 1: fused prep + bf16 MFMA dist, 16x16 tile per wave -------
// (round-0 proven kernel, verbatim; only change: also zero the done-counter)
__global__ __launch_bounds__(64) void dist_fused_kernel(
    const float* __restrict__ S, const int* __restrict__ labels,
    unsigned* __restrict__ masks, float* __restrict__ Dm, float* __restrict__ accum)
{
    const int l    = threadIdx.x;
    const int r    = l & 15;        // fragment row (A.m / B.n), also C.col
    const int half = l >> 4;        // k-base half*8; C.row base half*4
    const int jb = blockIdx.x * 16;
    const int ib = blockIdx.y * 16;
    const int kb = half * 8;

    // masks (y==0 blocks, 16 rows each) + accum/done zero (block 0,0)
    if (blockIdx.y == 0) {
        if (l < 16) {
            const int row = blockIdx.x * 16 + l;
            const int* lab = labels + row * LL;
            unsigned m = 0;
#pragma unroll
            for (int q = 0; q < LL; q++) m |= (lab[q] != 0 ? 1u : 0u) << q;
            masks[row] = m;
        }
        if (blockIdx.x == 0 && l == 0) {
            accum[0] = 0.0f;
            ((unsigned*)accum)[1] = 0u;
            ((unsigned*)accum)[2] = 0u;    // done-counter for k2 finalize
        }
    }

    const float* pA = S + (size_t)(ib + r) * DD + kb;
    const float* pB = S + (size_t)(jb + r) * DD + kb;

    f32x4 acc = {0.f, 0.f, 0.f, 0.f};
    float nA = 0.f, nB = 0.f;

    float4 ax = *(const float4*)pA, ay = *(const float4*)(pA + 4);
    float4 bx = *(const float4*)pB, by = *(const float4*)(pB + 4);

    for (int k0 = 0; k0 < DD; k0 += 32) {
        float4 nax, nay, nbx, nby;
        const int kn = k0 + 32;
        if (kn < DD) {              // uniform: prefetch next k-step
            nax = *(const float4*)(pA + kn); nay = *(const float4*)(pA + kn + 4);
            nbx = *(const float4*)(pB + kn); nby = *(const float4*)(pB + kn + 4);
        }
        short8 af = pack8_pk(ax, ay, nA);
        short8 bf = pack8_pk(bx, by, nB);
        acc = __builtin_amdgcn_mfma_f32_16x16x32_bf16(af, bf, acc, 0, 0, 0);
        ax = nax; ay = nay; bx = nbx; by = nby;
    }

    // norms: row ib+r covered by lanes {r, r+16, r+32, r+48} (disjoint k) -> reduce
    nA += __shfl_xor(nA, 16); nA += __shfl_xor(nA, 32);
    nB += __shfl_xor(nB, 16); nB += __shfl_xor(nB, 32);

    // C/D layout (verified): col = lane&15, row = half*4 + reg
    const int jc = jb + r;
    const float nj = nB;
#pragma unroll
    for (int p = 0; p < 4; p++) {
        const int ir = ib + half * 4 + p;
        const float ni = __shfl(nA, half * 4 + p);   // lane (half*4+p) holds row ib+half*4+p
        Dm[(size_t)ir * BN + jc] = dist_val(ni + nj - 2.f * acc[p], ir == jc);
    }
}

// ---------------- kernel 2: negative-sparse triplet + fused finalize ---------
// 128 blocks x 1 wave, 4 rows per block. All-register: 512 masks live as
// m[8] per lane; ballot gives the positive set per 64-chunk. Rows with no
// negatives (~60%, since P(neg pair) = (3/4)^24 ~ 0.001) exit before ever
// touching the distance row. The (pos, neg) pair loop is round-1's
// verified phase-2 structure. Last-done block (ticket) finalizes.
#define K2_BLOCKS 128
#define K2_ROWS   (BN / K2_BLOCKS)   // 4

__global__ __launch_bounds__(64) void triplet_kernel(
    const float* __restrict__ Dm, const unsigned* __restrict__ masks,
    float* __restrict__ accum, float* __restrict__ out)
{
    const int lane = threadIdx.x;

    unsigned m[8];
#pragma unroll
    for (int c = 0; c < 8; c++) m[c] = masks[c * 64 + lane];

    float bsum = 0.f; unsigned bcnt = 0;

    for (int rr = 0; rr < K2_ROWS; rr++) {
        const int i = blockIdx.x * K2_ROWS + rr;
        const unsigned mi = masks[i];          // uniform address -> scalar load (L2-hot)

        unsigned long long pb[8];
        unsigned long long anyneg = 0ull;
#pragma unroll
        for (int c = 0; c < 8; c++) {
            pb[c] = __ballot((mi & m[c]) != 0u);
            anyneg |= ~pb[c];
        }
        if (anyneg == 0ull) continue;          // wave-uniform: row contributes nothing

        const float* drow = Dm + (size_t)i * BN;
        float dv[8];
#pragma unroll
        for (int c = 0; c < 8; c++) dv[c] = drow[c * 64 + lane];

#pragma unroll
        for (int c = 0; c < 8; c++) {
            unsigned long long nb = ~pb[c];
            while (nb) {                       // wave-uniform, ~0.5 iters/row avg
                const int k = __ffsll(nb) - 1;
                nb &= nb - 1;
                const float dk = __shfl(dv[c], k);
#pragma unroll
                for (int c2 = 0; c2 < 8; c2++) {
                    if ((pb[c2] >> lane) & 1ull) {   // this lane's j is a positive
                        const float v = dv[c2] - dk;
                        bsum += fmaxf(v, 0.0f);
                        bcnt += (v > 1e-16f) ? 1u : 0u;
                    }
                }
            }
        }
    }

    // wave reduce
#pragma unroll
    for (int off = 32; off > 0; off >>= 1) {
        bsum += __shfl_down(bsum, off);
        bcnt += __shfl_down(bcnt, off);
    }
    if (lane == 0 && (bsum != 0.f || bcnt != 0u)) {
        atomicAdd(&accum[0], bsum);
        atomicAdd(&((unsigned*)accum)[1], bcnt);
    }

    // last-block-done finalize (release fence -> ticket -> acquire fence)
    __threadfence();
    if (lane == 0) {
        const unsigned t = atomicAdd(&((unsigned*)accum)[2], 1u);
        if (t == (unsigned)(K2_BLOCKS - 1)) {
            __threadfence();
            const float    s = atomicAdd(&accum[0], 0.0f);            // coherent read
            const unsigned c = atomicAdd(&((unsigned*)accum)[1], 0u); // coherent read
            out[0] = s / ((float)c + 1e-16f);
        }
    }
}

extern "C" void kernel_launch(void* const* d_in, const int* in_sizes, int n_in,
                              void* d_out, int out_size, void* d_ws, size_t ws_size,
                              hipStream_t stream) {
    const float* src    = (const float*)d_in[0];
    const int*   labels = (const int*)d_in[1];
    float* ws = (float*)d_ws;
    unsigned* masks = (unsigned*)ws;
    float*    Dm    = ws + BN;
    float*    accum = ws + BN + (size_t)BN * BN;

    hipLaunchKernelGGL(dist_fused_kernel, dim3(32, 32),   dim3(64), 0, stream,
                       src, labels, masks, Dm, accum);
    hipLaunchKernelGGL(triplet_kernel,    dim3(K2_BLOCKS), dim3(64), 0, stream,
                       Dm, masks, accum, (float*)d_out);
}